// Round 32
// baseline (296.638 us; speedup 1.0000x reference)
//
#include <hip/hip_runtime.h>
#include <hip/hip_bf16.h>

// AWQ dequant + GEMM, MI355X -- R32: counted-vmcnt double-buffered GEMM.
// Conventions (R26+ PASS): x fp32 [M,K]-C, q int32 [N,K]-C [0,16),
// s/z fp32 [G,N]-C, bias fp32 [N], out FP32 [M,N]-C.
// R31 hit the m97-structure plateau (MfmaUtil 36.6%, 818 TF): the
// __syncthreads vmcnt(0) drain stalls every K-tile. R32: LDS dbuf (2 sets),
// stage t+1 at top of iter t, s_waitcnt vmcnt(8) confirms t's loads (issued
// one full iteration ago) while t+1's 8 float across the MFMA block.
// Race-free: set (t+1)&1 last read in iter t-1, completed before its end
// barrier < stage issue. Raw s_barrier + sched_barrier(0) fencing (rule #18).

typedef __attribute__((ext_vector_type(8))) __bf16 bf16x8;
typedef __attribute__((ext_vector_type(4))) float f32x4;

#define BM 128
#define BN 128
#define BK 64
#define NTHREADS 256
#define NXCD 8

__device__ __forceinline__ unsigned int pk_bf16(float lo, float hi) {
  __hip_bfloat162 h = __float22bfloat162_rn(float2{lo, hi});  // v_cvt_pk_bf16_f32
  union { __hip_bfloat162 h; unsigned int u; } c; c.h = h;
  return c.u;
}

__device__ __forceinline__ void gload_lds16(const void* g, void* lds) {
  __builtin_amdgcn_global_load_lds(
      (const __attribute__((address_space(1))) unsigned int*)g,
      (__attribute__((address_space(3))) unsigned int*)lds, 16, 0, 0);
}

// ---- pre-pass 1: q int32 [N,K] -> Wb bf16 tile-blobs, T2 pre-swizzled.
__global__ __launch_bounds__(256)
void wdequant_kernel(const int* __restrict__ Q,
                     const float* __restrict__ S, const float* __restrict__ Z,
                     unsigned short* __restrict__ Wb, int N, int K, int GS)
{
  const unsigned int idx = blockIdx.x * 256 + threadIdx.x;
  const unsigned long long e = (unsigned long long)idx * 8;
  if (e >= (unsigned long long)N * K) return;
  const unsigned int n = (unsigned int)(e / (unsigned int)K);
  const unsigned int k = (unsigned int)(e % (unsigned int)K);
  const unsigned int g = k / (unsigned int)GS;
  const float s = S[(size_t)g * N + n];
  const float z = Z[(size_t)g * N + n];
  const int4 q0 = *reinterpret_cast<const int4*>(Q + e);
  const int4 q1 = *reinterpret_cast<const int4*>(Q + e + 4);
  const unsigned int u0 = pk_bf16((float)q0.x * s + z, (float)q0.y * s + z);
  const unsigned int u1 = pk_bf16((float)q0.z * s + z, (float)q0.w * s + z);
  const unsigned int u2 = pk_bf16((float)q1.x * s + z, (float)q1.y * s + z);
  const unsigned int u3 = pk_bf16((float)q1.z * s + z, (float)q1.w * s + z);
  const unsigned int ntile = n >> 7, row = n & 127;
  const unsigned int kt = k >> 6, col = k & 63;
  const unsigned int dst = (ntile * (K >> 6) + kt) * 8192u + row * 64u
                         + (col ^ ((row & 7) << 3));
  *reinterpret_cast<uint4*>(Wb + dst) = make_uint4(u0, u1, u2, u3);
}

// ---- pre-pass 2: x fp32 [M,K] -> Xb bf16 tile-blobs, T2 pre-swizzled.
__global__ __launch_bounds__(256)
void xconv_kernel(const float* __restrict__ X, unsigned short* __restrict__ Xb,
                  int M, int K)
{
  const unsigned int idx = blockIdx.x * 256 + threadIdx.x;
  const unsigned int e = idx * 8;
  if (e >= (unsigned int)(M * K)) return;
  const unsigned int m = e / (unsigned int)K;
  const unsigned int k = e % (unsigned int)K;
  const unsigned int mt = m >> 7, row = m & 127;
  const unsigned int kt = k >> 6, col = k & 63;
  const unsigned int dst = (mt * (K >> 6) + kt) * 8192u + row * 64u
                         + (col ^ ((row & 7) << 3));
  const float4 v0 = *reinterpret_cast<const float4*>(X + e);
  const float4 v1 = *reinterpret_cast<const float4*>(X + e + 4);
  *reinterpret_cast<uint4*>(Xb + dst) =
      make_uint4(pk_bf16(v0.x, v0.y), pk_bf16(v0.z, v0.w),
                 pk_bf16(v1.x, v1.y), pk_bf16(v1.z, v1.w));
}

// ---- GEMM: dual-DMA + counted-vmcnt double buffer.
__global__ __launch_bounds__(NTHREADS, 2)
void gemm_kernel(const unsigned short* __restrict__ Xb,
                 const unsigned short* __restrict__ Wb,
                 const float* __restrict__ Bias,
                 float* __restrict__ Out, int M, int N, int K)
{
  __shared__ unsigned short As[2][BM * BK];   // 2 x 16KB
  __shared__ unsigned short Bs[2][BN * BK];   // 2 x 16KB

  const int tid  = threadIdx.x;
  const int wave = tid >> 6;
  const int lane = tid & 63;

  const int nwg = gridDim.x;
  int bid = blockIdx.x;
  if ((nwg % NXCD) == 0) {
    const int cpx = nwg / NXCD;
    bid = (blockIdx.x % NXCD) * cpx + blockIdx.x / NXCD;
  }
  const int mtiles = M / BM;
  const int mt = bid % mtiles;
  const int nt = bid / mtiles;
  const int m0 = mt * BM;
  const int n0 = nt * BN;

  const int wm = (wave >> 1) * 64;
  const int wn = (wave & 1) * 64;

  f32x4 acc[4][4];
#pragma unroll
  for (int i = 0; i < 4; ++i)
#pragma unroll
    for (int j = 0; j < 4; ++j)
      acc[i][j] = (f32x4){0.f, 0.f, 0.f, 0.f};

  const int ktiles = K / BK;                   // 64
  const unsigned short* Ablob = Xb + (size_t)mt * ktiles * (BM * BK);
  const unsigned short* Bblob = Wb + (size_t)nt * ktiles * (BN * BK);

  // ---- prologue: stage Kt0 -> set 0, full drain once
  {
#pragma unroll
    for (int it = 0; it < 4; ++it) {
      const int chunk = wave * 4 + it;
      gload_lds16(Ablob + chunk * 512 + lane * 8, (char*)As[0] + chunk * 1024);
      gload_lds16(Bblob + chunk * 512 + lane * 8, (char*)Bs[0] + chunk * 1024);
    }
  }
  asm volatile("s_waitcnt vmcnt(0)" ::: "memory");
  __builtin_amdgcn_sched_barrier(0);
  __builtin_amdgcn_s_barrier();
  __builtin_amdgcn_sched_barrier(0);

  for (int kt = 0; kt < ktiles; ++kt) {
    const int cur = kt & 1;

    // ---- stage Kt kt+1 into set cur^1 (loads float across this iter's MFMA)
    if (kt + 1 < ktiles) {
      const unsigned short* asrc = Ablob + (size_t)(kt + 1) * (BM * BK);
      const unsigned short* bsrc = Bblob + (size_t)(kt + 1) * (BN * BK);
#pragma unroll
      for (int it = 0; it < 4; ++it) {
        const int chunk = wave * 4 + it;
        gload_lds16(asrc + chunk * 512 + lane * 8, (char*)As[cur ^ 1] + chunk * 1024);
        gload_lds16(bsrc + chunk * 512 + lane * 8, (char*)Bs[cur ^ 1] + chunk * 1024);
      }
      // confirm Kt kt's 8 loads (issued one iteration ago); keep kt+1's 8 in flight
      asm volatile("s_waitcnt vmcnt(8)" ::: "memory");
    } else {
      asm volatile("s_waitcnt vmcnt(0)" ::: "memory");
    }
    __builtin_amdgcn_sched_barrier(0);
    __builtin_amdgcn_s_barrier();          // all waves' Kt-kt loads visible
    __builtin_amdgcn_sched_barrier(0);

    // ---- MFMA: 2 phases (k-subtiles), 16 MFMA each, setprio role-split
#pragma unroll
    for (int kk = 0; kk < 2; ++kk) {
      const int klane = kk * 32 + (lane >> 4) * 8;
      bf16x8 a[4], b[4];
#pragma unroll
      for (int i = 0; i < 4; ++i) {
        const int row = wm + i * 16 + (lane & 15);
        a[i] = *reinterpret_cast<const bf16x8*>(
            &As[cur][row * BK + (klane ^ ((row & 7) << 3))]);
      }
#pragma unroll
      for (int j = 0; j < 4; ++j) {
        const int row = wn + j * 16 + (lane & 15);
        b[j] = *reinterpret_cast<const bf16x8*>(
            &Bs[cur][row * BK + (klane ^ ((row & 7) << 3))]);
      }
      __builtin_amdgcn_s_setprio(1);
#pragma unroll
      for (int i = 0; i < 4; ++i)
#pragma unroll
        for (int j = 0; j < 4; ++j)
          acc[i][j] = __builtin_amdgcn_mfma_f32_16x16x32_bf16(a[i], b[j], acc[i][j], 0, 0, 0);
      __builtin_amdgcn_s_setprio(0);
    }

    __builtin_amdgcn_sched_barrier(0);
    __builtin_amdgcn_s_barrier();          // set-cur reads done before its rewrite
    __builtin_amdgcn_sched_barrier(0);
  }

  // ---- Epilogue (C/D map m89/m91): col=lane&15, row=(lane>>4)*4+r
  const int colbase = n0 + wn + (lane & 15);
  const int rowbase = m0 + wm + ((lane >> 4) << 2);
#pragma unroll
  for (int j = 0; j < 4; ++j) {
    const int col = colbase + j * 16;
    const float bv = Bias[col];
#pragma unroll
    for (int i = 0; i < 4; ++i) {
      const int row = rowbase + i * 16;
#pragma unroll
      for (int r = 0; r < 4; ++r)
        Out[(size_t)(row + r) * N + col] = acc[i][j][r] + bv;
    }
  }
}

extern "C" void kernel_launch(void* const* d_in, const int* in_sizes, int n_in,
                              void* d_out, int out_size, void* d_ws, size_t ws_size,
                              hipStream_t stream) {
  const float* x    = (const float*)d_in[0];
  const int*   q    = (const int*)d_in[1];
  const float* s    = (const float*)d_in[2];
  const float* z    = (const float*)d_in[3];
  const float* bias = (const float*)d_in[4];
  float*       out  = (float*)d_out;

  const int N  = in_sizes[4];              // 11008
  const int K  = in_sizes[1] / N;          // 4096
  const int M  = in_sizes[0] / K;          // 2048
  const int G  = in_sizes[2] / N;          // 32
  const int GS = K / G;                    // 128

  unsigned short* Wb = (unsigned short*)d_ws;            // N*K bf16 = 90MB
  unsigned short* Xb = Wb + (size_t)N * K;               // M*K bf16 = 17MB

  const int wblocks = (int)(((size_t)N * K / 8 + 255) / 256);
  wdequant_kernel<<<wblocks, 256, 0, stream>>>(q, s, z, Wb, N, K, GS);
  const int xblocks = (M * K / 8 + 255) / 256;
  xconv_kernel<<<xblocks, 256, 0, stream>>>(x, Xb, M, K);

  const int grid = (M / BM) * (N / BN);                  // 1376 = 8*172
  gemm_kernel<<<grid, NTHREADS, 0, stream>>>(Xb, Wb, bias, out, M, N, K);
}

// Round 33
// 263.423 us; speedup vs baseline: 1.1261x; 1.1261x over previous
//
#include <hip/hip_runtime.h>
#include <hip/hip_bf16.h>

// AWQ dequant + GEMM, MI355X -- R33: 8-wave 128x256 tile, BK=32, 3-deep
// counted-vmcnt LDS ring (T3+T4), setprio (T5), XCD swizzle (T1), blob
// pre-swizzle (T2, rule#21).
// Conventions (R26+ PASS): x fp32 [M,K]-C, q int32 [N,K]-C [0,16),
// s/z fp32 [G,N]-C, bias fp32 [N], out FP32 [M,N]-C.
// R32 lesson: dbuf at 64KB killed occupancy; R33 keeps 72KB (2 blocks/CU)
// and waits vmcnt(6) = confirm loads issued 2 iterations (~800cyc) ago.
// Race audit: set (t+2)%3 written at iter t was last read at t-1 (barrier-
// separated); reads of set t%3 confirmed per-wave by vmcnt(6) + s_barrier.

typedef __attribute__((ext_vector_type(8))) __bf16 bf16x8;
typedef __attribute__((ext_vector_type(4))) float f32x4;

#define BM 128
#define BN 256
#define BK 32
#define NTHREADS 512
#define NXCD 8

__device__ __forceinline__ unsigned int pk_bf16(float lo, float hi) {
  __hip_bfloat162 h = __float22bfloat162_rn(float2{lo, hi});  // v_cvt_pk_bf16_f32
  union { __hip_bfloat162 h; unsigned int u; } c; c.h = h;
  return c.u;
}

__device__ __forceinline__ void gload_lds16(const void* g, void* lds) {
  __builtin_amdgcn_global_load_lds(
      (const __attribute__((address_space(1))) unsigned int*)g,
      (__attribute__((address_space(3))) unsigned int*)lds, 16, 0, 0);
}

// Bank-swizzle for 32-col (64B) rows: col-block (16B) cb ^= (row>>1)&3.
// 16-lane row-groups then hit 8 distinct banks -> 2-way (free).

// ---- pre-pass 1: q int32 [N,K] -> Wb bf16 blobs (256-row x 32-col tiles).
__global__ __launch_bounds__(256)
void wdequant_kernel(const int* __restrict__ Q,
                     const float* __restrict__ S, const float* __restrict__ Z,
                     unsigned short* __restrict__ Wb, int N, int K, int GS)
{
  const unsigned int idx = blockIdx.x * 256 + threadIdx.x;
  const unsigned long long e = (unsigned long long)idx * 8;
  if (e >= (unsigned long long)N * K) return;
  const unsigned int n = (unsigned int)(e / (unsigned int)K);
  const unsigned int k = (unsigned int)(e % (unsigned int)K);
  const unsigned int g = k / (unsigned int)GS;
  const float s = S[(size_t)g * N + n];
  const float z = Z[(size_t)g * N + n];
  const int4 q0 = *reinterpret_cast<const int4*>(Q + e);
  const int4 q1 = *reinterpret_cast<const int4*>(Q + e + 4);
  const unsigned int u0 = pk_bf16((float)q0.x * s + z, (float)q0.y * s + z);
  const unsigned int u1 = pk_bf16((float)q0.z * s + z, (float)q0.w * s + z);
  const unsigned int u2 = pk_bf16((float)q1.x * s + z, (float)q1.y * s + z);
  const unsigned int u3 = pk_bf16((float)q1.z * s + z, (float)q1.w * s + z);
  const unsigned int nt2 = n >> 8, row = n & 255;
  const unsigned int kt = k >> 5;
  const unsigned int cb = ((k & 31) >> 3) ^ ((row >> 1) & 3);
  const unsigned int dst = (nt2 * (K >> 5) + kt) * 8192u + row * 32u + cb * 8u;
  *reinterpret_cast<uint4*>(Wb + dst) = make_uint4(u0, u1, u2, u3);
}

// ---- pre-pass 2: x fp32 [M,K] -> Xb bf16 blobs (128-row x 32-col tiles).
__global__ __launch_bounds__(256)
void xconv_kernel(const float* __restrict__ X, unsigned short* __restrict__ Xb,
                  int M, int K)
{
  const unsigned int idx = blockIdx.x * 256 + threadIdx.x;
  const unsigned int e = idx * 8;
  if (e >= (unsigned int)(M * K)) return;
  const unsigned int m = e / (unsigned int)K;
  const unsigned int k = e % (unsigned int)K;
  const unsigned int mt = m >> 7, row = m & 127;
  const unsigned int kt = k >> 5;
  const unsigned int cb = ((k & 31) >> 3) ^ ((row >> 1) & 3);
  const unsigned int dst = (mt * (K >> 5) + kt) * 4096u + row * 32u + cb * 8u;
  const float4 v0 = *reinterpret_cast<const float4*>(X + e);
  const float4 v1 = *reinterpret_cast<const float4*>(X + e + 4);
  *reinterpret_cast<uint4*>(Xb + dst) =
      make_uint4(pk_bf16(v0.x, v0.y), pk_bf16(v0.z, v0.w),
                 pk_bf16(v1.x, v1.y), pk_bf16(v1.z, v1.w));
}

// ---- GEMM: 8 waves, 3-deep ring, counted vmcnt.
__global__ __launch_bounds__(NTHREADS, 4)
void gemm_kernel(const unsigned short* __restrict__ Xb,
                 const unsigned short* __restrict__ Wb,
                 const float* __restrict__ Bias,
                 float* __restrict__ Out, int M, int N, int K)
{
  // ring: set s: A at s*12288, B at s*12288+4096 (ushorts). 3*24KB = 72KB.
  __shared__ unsigned short LDS[3 * 12288];

  const int tid  = threadIdx.x;
  const int wave = tid >> 6;               // 0..7
  const int lane = tid & 63;

  const int nwg = gridDim.x;               // 688 = 8*86
  int bid = blockIdx.x;
  if ((nwg % NXCD) == 0) {
    const int cpx = nwg / NXCD;
    bid = (blockIdx.x % NXCD) * cpx + blockIdx.x / NXCD;
  }
  const int mtiles = M / BM;               // 16
  const int mt = bid % mtiles;
  const int nt = bid / mtiles;
  const int m0 = mt * BM;
  const int n0 = nt * BN;

  const int wm = (wave >> 2) * 64;         // 2x4 wave grid: 64 rows x 64 cols each
  const int wn = (wave & 3) * 64;

  f32x4 acc[4][4];
#pragma unroll
  for (int i = 0; i < 4; ++i)
#pragma unroll
    for (int j = 0; j < 4; ++j)
      acc[i][j] = (f32x4){0.f, 0.f, 0.f, 0.f};

  const int ktiles = K / BK;               // 128
  const unsigned short* Ablob = Xb + (size_t)mt * ktiles * 4096;  // 8KB tiles
  const unsigned short* Bblob = Wb + (size_t)nt * ktiles * 8192;  // 16KB tiles

  // stage(t) into set t%3: wave w -> A-chunk w (1KB), B-chunks 2w, 2w+1.
#define STAGE(t)                                                               \
  {                                                                            \
    const unsigned short* asrc = Ablob + (size_t)(t) * 4096;                   \
    const unsigned short* bsrc = Bblob + (size_t)(t) * 8192;                   \
    char* As = (char*)&LDS[((t) % 3) * 12288];                                 \
    char* Bs = As + 8192;                                                      \
    gload_lds16(asrc + wave * 512 + lane * 8, As + wave * 1024);               \
    gload_lds16(bsrc + (wave * 2) * 512 + lane * 8, Bs + (wave * 2) * 1024);   \
    gload_lds16(bsrc + (wave * 2 + 1) * 512 + lane * 8,                        \
                Bs + (wave * 2 + 1) * 1024);                                   \
  }

  // ---- prologue: stage t=0,1 (6 loads/wave outstanding)
  STAGE(0);
  STAGE(1);

  const int klane = (lane >> 4) * 8;       // k-chunk 0/8/16/24
  const int lrow  = lane & 15;

  for (int kt = 0; kt < ktiles; ++kt) {
    if (kt + 2 < ktiles) {
      STAGE(kt + 2);
      asm volatile("s_waitcnt vmcnt(6)" ::: "memory");   // confirm tile kt
    } else {
      asm volatile("s_waitcnt vmcnt(0)" ::: "memory");
    }
    __builtin_amdgcn_sched_barrier(0);
    __builtin_amdgcn_s_barrier();          // all waves' tile-kt loads visible
    __builtin_amdgcn_sched_barrier(0);

    const unsigned short* As = &LDS[(kt % 3) * 12288];
    const unsigned short* Bs = As + 4096;

    bf16x8 a[4], b[4];
#pragma unroll
    for (int i = 0; i < 4; ++i) {
      const int r = wm + i * 16 + lrow;
      const int cb = (klane >> 3) ^ ((r >> 1) & 3);
      a[i] = *reinterpret_cast<const bf16x8*>(&As[r * 32 + cb * 8]);
    }
#pragma unroll
    for (int j = 0; j < 4; ++j) {
      const int r = wn + j * 16 + lrow;
      const int cb = (klane >> 3) ^ ((r >> 1) & 3);
      b[j] = *reinterpret_cast<const bf16x8*>(&Bs[r * 32 + cb * 8]);
    }

    __builtin_amdgcn_s_setprio(1);
#pragma unroll
    for (int i = 0; i < 4; ++i)
#pragma unroll
      for (int j = 0; j < 4; ++j)
        acc[i][j] = __builtin_amdgcn_mfma_f32_16x16x32_bf16(a[i], b[j], acc[i][j], 0, 0, 0);
    __builtin_amdgcn_s_setprio(0);

    __builtin_amdgcn_sched_barrier(0);
    __builtin_amdgcn_s_barrier();          // reads of set kt%3 done before rewrite
    __builtin_amdgcn_sched_barrier(0);
  }
#undef STAGE

  // ---- Epilogue (C/D map m89/m91): col=lane&15, row=(lane>>4)*4+r
  const int colbase = n0 + wn + (lane & 15);
  const int rowbase = m0 + wm + ((lane >> 4) << 2);
#pragma unroll
  for (int j = 0; j < 4; ++j) {
    const int col = colbase + j * 16;
    const float bv = Bias[col];
#pragma unroll
    for (int i = 0; i < 4; ++i) {
      const int row = rowbase + i * 16;
#pragma unroll
      for (int r = 0; r < 4; ++r)
        Out[(size_t)(row + r) * N + col] = acc[i][j][r] + bv;
    }
  }
}

extern "C" void kernel_launch(void* const* d_in, const int* in_sizes, int n_in,
                              void* d_out, int out_size, void* d_ws, size_t ws_size,
                              hipStream_t stream) {
  const float* x    = (const float*)d_in[0];
  const int*   q    = (const int*)d_in[1];
  const float* s    = (const float*)d_in[2];
  const float* z    = (const float*)d_in[3];
  const float* bias = (const float*)d_in[4];
  float*       out  = (float*)d_out;

  const int N  = in_sizes[4];              // 11008
  const int K  = in_sizes[1] / N;          // 4096
  const int M  = in_sizes[0] / K;          // 2048
  const int G  = in_sizes[2] / N;          // 32
  const int GS = K / G;                    // 128

  unsigned short* Wb = (unsigned short*)d_ws;            // N*K bf16 = 90MB
  unsigned short* Xb = Wb + (size_t)N * K;               // M*K bf16 = 17MB

  const int wblocks = (int)(((size_t)N * K / 8 + 255) / 256);
  wdequant_kernel<<<wblocks, 256, 0, stream>>>(q, s, z, Wb, N, K, GS);
  const int xblocks = (M * K / 8 + 255) / 256;
  xconv_kernel<<<xblocks, 256, 0, stream>>>(x, Xb, M, K);

  const int grid = (M / BM) * (N / BN);                  // 16*43 = 688 = 8*86
  gemm_kernel<<<grid, NTHREADS, 0, stream>>>(Xb, Wb, bias, out, M, N, K);
}

// Round 34
// 261.606 us; speedup vs baseline: 1.1339x; 1.0069x over previous
//
#include <hip/hip_runtime.h>
#include <hip/hip_bf16.h>

// AWQ dequant + GEMM, MI355X -- R34: R33's ring-pipeline engine, rebalanced
// to 128x128/4-wave/BK=32 (ring-3, 48KB -> 3 blocks/CU) to kill the tail.
// R33 post-mortem: steady-state util ~61% but grid 688 @ 2 blocks/CU = 1.34
// rounds -> 33% tail idle -> observed 41%. R34: grid 1376 @ 3 blocks/CU =
// 1.79 rounds -> ~10% tail. Engine unchanged: counted vmcnt(8), raw
// s_barrier + sched_barrier(0) fencing, setprio MFMA cluster, T2 blob
// pre-swizzle (rule#21), T1 XCD-bijective block swizzle.
// Conventions (R26+ PASS): x fp32 [M,K]-C, q int32 [N,K]-C [0,16),
// s/z fp32 [G,N]-C, bias fp32 [N], out FP32 [M,N]-C.

typedef __attribute__((ext_vector_type(8))) __bf16 bf16x8;
typedef __attribute__((ext_vector_type(4))) float f32x4;

#define BM 128
#define BN 128
#define BK 32
#define NTHREADS 256
#define NXCD 8

__device__ __forceinline__ unsigned int pk_bf16(float lo, float hi) {
  __hip_bfloat162 h = __float22bfloat162_rn(float2{lo, hi});  // v_cvt_pk_bf16_f32
  union { __hip_bfloat162 h; unsigned int u; } c; c.h = h;
  return c.u;
}

__device__ __forceinline__ void gload_lds16(const void* g, void* lds) {
  __builtin_amdgcn_global_load_lds(
      (const __attribute__((address_space(1))) unsigned int*)g,
      (__attribute__((address_space(3))) unsigned int*)lds, 16, 0, 0);
}

// Blob swizzle (both tensors, 128-row x 32-col tiles of 4096 ushorts):
//   dst = tile*4096 + row*32 + (cb ^ ((row>>1)&3))*8 + (k&7),  cb=(k&31)>>3.
// Bank audit: 16-lane column reads land 2 lanes/bank (free; R33 measured 0).

// ---- pre-pass 1: q int32 [N,K] -> Wb bf16 blobs.
__global__ __launch_bounds__(256)
void wdequant_kernel(const int* __restrict__ Q,
                     const float* __restrict__ S, const float* __restrict__ Z,
                     unsigned short* __restrict__ Wb, int N, int K, int GS)
{
  const unsigned int idx = blockIdx.x * 256 + threadIdx.x;
  const unsigned long long e = (unsigned long long)idx * 8;
  if (e >= (unsigned long long)N * K) return;
  const unsigned int n = (unsigned int)(e / (unsigned int)K);
  const unsigned int k = (unsigned int)(e % (unsigned int)K);
  const unsigned int g = k / (unsigned int)GS;
  const float s = S[(size_t)g * N + n];
  const float z = Z[(size_t)g * N + n];
  const int4 q0 = *reinterpret_cast<const int4*>(Q + e);
  const int4 q1 = *reinterpret_cast<const int4*>(Q + e + 4);
  const unsigned int u0 = pk_bf16((float)q0.x * s + z, (float)q0.y * s + z);
  const unsigned int u1 = pk_bf16((float)q0.z * s + z, (float)q0.w * s + z);
  const unsigned int u2 = pk_bf16((float)q1.x * s + z, (float)q1.y * s + z);
  const unsigned int u3 = pk_bf16((float)q1.z * s + z, (float)q1.w * s + z);
  const unsigned int nt2 = n >> 7, row = n & 127;
  const unsigned int kt = k >> 5;
  const unsigned int cb = ((k & 31) >> 3) ^ ((row >> 1) & 3);
  const unsigned int dst = (nt2 * (K >> 5) + kt) * 4096u + row * 32u + cb * 8u;
  *reinterpret_cast<uint4*>(Wb + dst) = make_uint4(u0, u1, u2, u3);
}

// ---- pre-pass 2: x fp32 [M,K] -> Xb bf16 blobs.
__global__ __launch_bounds__(256)
void xconv_kernel(const float* __restrict__ X, unsigned short* __restrict__ Xb,
                  int M, int K)
{
  const unsigned int idx = blockIdx.x * 256 + threadIdx.x;
  const unsigned int e = idx * 8;
  if (e >= (unsigned int)(M * K)) return;
  const unsigned int m = e / (unsigned int)K;
  const unsigned int k = e % (unsigned int)K;
  const unsigned int mt = m >> 7, row = m & 127;
  const unsigned int kt = k >> 5;
  const unsigned int cb = ((k & 31) >> 3) ^ ((row >> 1) & 3);
  const unsigned int dst = (mt * (K >> 5) + kt) * 4096u + row * 32u + cb * 8u;
  const float4 v0 = *reinterpret_cast<const float4*>(X + e);
  const float4 v1 = *reinterpret_cast<const float4*>(X + e + 4);
  *reinterpret_cast<uint4*>(Xb + dst) =
      make_uint4(pk_bf16(v0.x, v0.y), pk_bf16(v0.z, v0.w),
                 pk_bf16(v1.x, v1.y), pk_bf16(v1.z, v1.w));
}

// ---- GEMM: 4 waves, 3-deep ring, counted vmcnt.
__global__ __launch_bounds__(NTHREADS, 3)
void gemm_kernel(const unsigned short* __restrict__ Xb,
                 const unsigned short* __restrict__ Wb,
                 const float* __restrict__ Bias,
                 float* __restrict__ Out, int M, int N, int K)
{
  // ring set s: A at s*8192, B at s*8192+4096 (ushorts). 3 x 16KB = 48KB.
  __shared__ unsigned short LDS[3 * 8192];

  const int tid  = threadIdx.x;
  const int wave = tid >> 6;               // 0..3
  const int lane = tid & 63;

  const int nwg = gridDim.x;               // 1376 = 8*172
  int bid = blockIdx.x;
  if ((nwg % NXCD) == 0) {
    const int cpx = nwg / NXCD;
    bid = (blockIdx.x % NXCD) * cpx + blockIdx.x / NXCD;
  }
  const int mtiles = M / BM;               // 16
  const int mt = bid % mtiles;             // mt fastest -> W-panel L2 reuse
  const int nt = bid / mtiles;
  const int m0 = mt * BM;
  const int n0 = nt * BN;

  const int wm = (wave >> 1) * 64;         // 2x2 wave grid
  const int wn = (wave & 1) * 64;

  f32x4 acc[4][4];
#pragma unroll
  for (int i = 0; i < 4; ++i)
#pragma unroll
    for (int j = 0; j < 4; ++j)
      acc[i][j] = (f32x4){0.f, 0.f, 0.f, 0.f};

  const int ktiles = K / BK;               // 128
  const unsigned short* Ablob = Xb + (size_t)mt * ktiles * 4096;  // 8KB tiles
  const unsigned short* Bblob = Wb + (size_t)nt * ktiles * 4096;  // 8KB tiles

  // stage(t) into set t%3: wave w -> A-chunks 2w,2w+1; B-chunks 2w,2w+1 (1KB each)
#define STAGE(t)                                                               \
  {                                                                            \
    const unsigned short* asrc = Ablob + (size_t)(t) * 4096;                   \
    const unsigned short* bsrc = Bblob + (size_t)(t) * 4096;                   \
    char* As = (char*)&LDS[((t) % 3) * 8192];                                  \
    char* Bs = As + 8192;                                                      \
    gload_lds16(asrc + (wave * 2) * 512 + lane * 8, As + (wave * 2) * 1024);   \
    gload_lds16(asrc + (wave * 2 + 1) * 512 + lane * 8,                        \
                As + (wave * 2 + 1) * 1024);                                   \
    gload_lds16(bsrc + (wave * 2) * 512 + lane * 8, Bs + (wave * 2) * 1024);   \
    gload_lds16(bsrc + (wave * 2 + 1) * 512 + lane * 8,                        \
                Bs + (wave * 2 + 1) * 1024);                                   \
  }

  // ---- prologue: stage t=0,1 (8 loads/wave outstanding)
  STAGE(0);
  STAGE(1);

  const int klane = (lane >> 4) * 8;       // k-chunk 0/8/16/24
  const int lrow  = lane & 15;

  for (int kt = 0; kt < ktiles; ++kt) {
    if (kt + 2 < ktiles) {
      STAGE(kt + 2);
      asm volatile("s_waitcnt vmcnt(8)" ::: "memory");   // confirm tile kt
    } else {
      asm volatile("s_waitcnt vmcnt(0)" ::: "memory");
    }
    __builtin_amdgcn_sched_barrier(0);
    __builtin_amdgcn_s_barrier();          // all waves' tile-kt loads visible
    __builtin_amdgcn_sched_barrier(0);

    const unsigned short* As = &LDS[(kt % 3) * 8192];
    const unsigned short* Bs = As + 4096;

    bf16x8 a[4], b[4];
#pragma unroll
    for (int i = 0; i < 4; ++i) {
      const int r = wm + i * 16 + lrow;
      const int cb = (klane >> 3) ^ ((r >> 1) & 3);
      a[i] = *reinterpret_cast<const bf16x8*>(&As[r * 32 + cb * 8]);
    }
#pragma unroll
    for (int j = 0; j < 4; ++j) {
      const int r = wn + j * 16 + lrow;
      const int cb = (klane >> 3) ^ ((r >> 1) & 3);
      b[j] = *reinterpret_cast<const bf16x8*>(&Bs[r * 32 + cb * 8]);
    }

    __builtin_amdgcn_s_setprio(1);
#pragma unroll
    for (int i = 0; i < 4; ++i)
#pragma unroll
      for (int j = 0; j < 4; ++j)
        acc[i][j] = __builtin_amdgcn_mfma_f32_16x16x32_bf16(a[i], b[j], acc[i][j], 0, 0, 0);
    __builtin_amdgcn_s_setprio(0);

    __builtin_amdgcn_sched_barrier(0);
    __builtin_amdgcn_s_barrier();          // set kt%3 reads done before rewrite
    __builtin_amdgcn_sched_barrier(0);
  }
#undef STAGE

  // ---- Epilogue (C/D map m89/m91): col=lane&15, row=(lane>>4)*4+r
  const int colbase = n0 + wn + (lane & 15);
  const int rowbase = m0 + wm + ((lane >> 4) << 2);
#pragma unroll
  for (int j = 0; j < 4; ++j) {
    const int col = colbase + j * 16;
    const float bv = Bias[col];
#pragma unroll
    for (int i = 0; i < 4; ++i) {
      const int row = rowbase + i * 16;
#pragma unroll
      for (int r = 0; r < 4; ++r)
        Out[(size_t)(row + r) * N + col] = acc[i][j][r] + bv;
    }
  }
}

extern "C" void kernel_launch(void* const* d_in, const int* in_sizes, int n_in,
                              void* d_out, int out_size, void* d_ws, size_t ws_size,
                              hipStream_t stream) {
  const float* x    = (const float*)d_in[0];
  const int*   q    = (const int*)d_in[1];
  const float* s    = (const float*)d_in[2];
  const float* z    = (const float*)d_in[3];
  const float* bias = (const float*)d_in[4];
  float*       out  = (float*)d_out;

  const int N  = in_sizes[4];              // 11008
  const int K  = in_sizes[1] / N;          // 4096
  const int M  = in_sizes[0] / K;          // 2048
  const int G  = in_sizes[2] / N;          // 32
  const int GS = K / G;                    // 128

  unsigned short* Wb = (unsigned short*)d_ws;            // N*K bf16 = 90MB
  unsigned short* Xb = Wb + (size_t)N * K;               // M*K bf16 = 17MB

  const int wblocks = (int)(((size_t)N * K / 8 + 255) / 256);
  wdequant_kernel<<<wblocks, 256, 0, stream>>>(q, s, z, Wb, N, K, GS);
  const int xblocks = (M * K / 8 + 255) / 256;
  xconv_kernel<<<xblocks, 256, 0, stream>>>(x, Xb, M, K);

  const int grid = (M / BM) * (N / BN);                  // 16*86 = 1376
  gemm_kernel<<<grid, NTHREADS, 0, stream>>>(Xb, Wb, bias, out, M, N, K);
}

// Round 35
// 258.813 us; speedup vs baseline: 1.1461x; 1.0108x over previous
//
#include <hip/hip_runtime.h>
#include <hip/hip_bf16.h>

// AWQ dequant + GEMM, MI355X -- R35: unroll-2 reg-pipelined ring-3.
// R34 post-mortem: 41% MfmaUtil IS the steady state (tail theory refuted) --
// engine is LDS-read/barrier limited (MFMA:ds_read = 2.0, 1 barrier pair per
// 16-MFMA cluster). R35: process 2 K-tiles per iter, one vmcnt(4)+barrier for
// both, kt+1 frag-reads interleave with MFMA(kt), STAGE(kt+3) hides under
// MFMA(kt+1). 3 barriers per 2 tiles (was 4), 32 MFMA per barrier-pair.
// Race audit in comments. Geometry unchanged: 128x128, BK=32, 4 waves,
// ring-3 = 48KB, 3 blocks/CU, grid 1376 = 8*172 (XCD-bijective).
// Conventions (R26+ PASS): x fp32 [M,K]-C, q int32 [N,K]-C [0,16),
// s/z fp32 [G,N]-C, bias fp32 [N], out FP32 [M,N]-C.

typedef __attribute__((ext_vector_type(8))) __bf16 bf16x8;
typedef __attribute__((ext_vector_type(4))) float f32x4;

#define BM 128
#define BN 128
#define BK 32
#define NTHREADS 256
#define NXCD 8

__device__ __forceinline__ unsigned int pk_bf16(float lo, float hi) {
  __hip_bfloat162 h = __float22bfloat162_rn(float2{lo, hi});  // v_cvt_pk_bf16_f32
  union { __hip_bfloat162 h; unsigned int u; } c; c.h = h;
  return c.u;
}

__device__ __forceinline__ void gload_lds16(const void* g, void* lds) {
  __builtin_amdgcn_global_load_lds(
      (const __attribute__((address_space(1))) unsigned int*)g,
      (__attribute__((address_space(3))) unsigned int*)lds, 16, 0, 0);
}

// ---- pre-pass 1: q int32 [N,K] -> Wb bf16 blobs (128x32 tiles, pre-swizzled).
__global__ __launch_bounds__(256)
void wdequant_kernel(const int* __restrict__ Q,
                     const float* __restrict__ S, const float* __restrict__ Z,
                     unsigned short* __restrict__ Wb, int N, int K, int GS)
{
  const unsigned int idx = blockIdx.x * 256 + threadIdx.x;
  const unsigned long long e = (unsigned long long)idx * 8;
  if (e >= (unsigned long long)N * K) return;
  const unsigned int n = (unsigned int)(e / (unsigned int)K);
  const unsigned int k = (unsigned int)(e % (unsigned int)K);
  const unsigned int g = k / (unsigned int)GS;
  const float s = S[(size_t)g * N + n];
  const float z = Z[(size_t)g * N + n];
  const int4 q0 = *reinterpret_cast<const int4*>(Q + e);
  const int4 q1 = *reinterpret_cast<const int4*>(Q + e + 4);
  const unsigned int u0 = pk_bf16((float)q0.x * s + z, (float)q0.y * s + z);
  const unsigned int u1 = pk_bf16((float)q0.z * s + z, (float)q0.w * s + z);
  const unsigned int u2 = pk_bf16((float)q1.x * s + z, (float)q1.y * s + z);
  const unsigned int u3 = pk_bf16((float)q1.z * s + z, (float)q1.w * s + z);
  const unsigned int nt2 = n >> 7, row = n & 127;
  const unsigned int kt = k >> 5;
  const unsigned int cb = ((k & 31) >> 3) ^ ((row >> 1) & 3);
  const unsigned int dst = (nt2 * (K >> 5) + kt) * 4096u + row * 32u + cb * 8u;
  *reinterpret_cast<uint4*>(Wb + dst) = make_uint4(u0, u1, u2, u3);
}

// ---- pre-pass 2: x fp32 [M,K] -> Xb bf16 blobs (128x32 tiles, pre-swizzled).
__global__ __launch_bounds__(256)
void xconv_kernel(const float* __restrict__ X, unsigned short* __restrict__ Xb,
                  int M, int K)
{
  const unsigned int idx = blockIdx.x * 256 + threadIdx.x;
  const unsigned int e = idx * 8;
  if (e >= (unsigned int)(M * K)) return;
  const unsigned int m = e / (unsigned int)K;
  const unsigned int k = e % (unsigned int)K;
  const unsigned int mt = m >> 7, row = m & 127;
  const unsigned int kt = k >> 5;
  const unsigned int cb = ((k & 31) >> 3) ^ ((row >> 1) & 3);
  const unsigned int dst = (mt * (K >> 5) + kt) * 4096u + row * 32u + cb * 8u;
  const float4 v0 = *reinterpret_cast<const float4*>(X + e);
  const float4 v1 = *reinterpret_cast<const float4*>(X + e + 4);
  *reinterpret_cast<uint4*>(Xb + dst) =
      make_uint4(pk_bf16(v0.x, v0.y), pk_bf16(v0.z, v0.w),
                 pk_bf16(v1.x, v1.y), pk_bf16(v1.z, v1.w));
}

// ---- GEMM: 4 waves, ring-3, unroll-2 reg-pipelined.
__global__ __launch_bounds__(NTHREADS, 3)
void gemm_kernel(const unsigned short* __restrict__ Xb,
                 const unsigned short* __restrict__ Wb,
                 const float* __restrict__ Bias,
                 float* __restrict__ Out, int M, int N, int K)
{
  __shared__ unsigned short LDS[3 * 8192];   // set s: A @ s*8192, B @ +4096

  const int tid  = threadIdx.x;
  const int wave = tid >> 6;
  const int lane = tid & 63;

  const int nwg = gridDim.x;                 // 1376 = 8*172
  int bid = blockIdx.x;
  if ((nwg % NXCD) == 0) {
    const int cpx = nwg / NXCD;
    bid = (blockIdx.x % NXCD) * cpx + blockIdx.x / NXCD;
  }
  const int mtiles = M / BM;
  const int mt = bid % mtiles;
  const int nt = bid / mtiles;
  const int m0 = mt * BM;
  const int n0 = nt * BN;

  const int wm = (wave >> 1) * 64;
  const int wn = (wave & 1) * 64;

  f32x4 acc[4][4];
#pragma unroll
  for (int i = 0; i < 4; ++i)
#pragma unroll
    for (int j = 0; j < 4; ++j)
      acc[i][j] = (f32x4){0.f, 0.f, 0.f, 0.f};

  const int ktiles = K / BK;                 // 128 (even)
  const unsigned short* Ablob = Xb + (size_t)mt * ktiles * 4096;
  const unsigned short* Bblob = Wb + (size_t)nt * ktiles * 4096;

#define STAGE(t)                                                               \
  {                                                                            \
    const unsigned short* asrc = Ablob + (size_t)(t) * 4096;                   \
    const unsigned short* bsrc = Bblob + (size_t)(t) * 4096;                   \
    char* As_ = (char*)&LDS[((t) % 3) * 8192];                                 \
    char* Bs_ = As_ + 8192;                                                    \
    gload_lds16(asrc + (wave * 2) * 512 + lane * 8, As_ + (wave * 2) * 1024);  \
    gload_lds16(asrc + (wave * 2 + 1) * 512 + lane * 8,                        \
                As_ + (wave * 2 + 1) * 1024);                                  \
    gload_lds16(bsrc + (wave * 2) * 512 + lane * 8, Bs_ + (wave * 2) * 1024);  \
    gload_lds16(bsrc + (wave * 2 + 1) * 512 + lane * 8,                        \
                Bs_ + (wave * 2 + 1) * 1024);                                  \
  }

  // prologue: tiles 0,1 in flight (8 loads/wave)
  STAGE(0);
  STAGE(1);

  const int klane = (lane >> 4) * 8;
  const int lrow  = lane & 15;

  for (int kt = 0; kt < ktiles; kt += 2) {
    // 1. stage kt+2 (into set (kt+2)%3 -- its last readers finished at iter kt-2's
    //    end barrier)
    if (kt + 2 < ktiles) {
      STAGE(kt + 2);
      // in flight: kt+1 was... wait: entering this iter in-flight = {kt, kt+1}?
      // steady state: {kt (staged top of prev iter... )}; see audit: after
      // STAGE(kt+2): {kt+1's remnants?, kt+2:4, kt+3-staged-prev-mid? }
      // conservative accounting: stages outstanding = kt+2 (4) + kt+3? not yet.
      // We require kt,kt+1 visible: leave only kt+2's 4 unconfirmed.
      asm volatile("s_waitcnt vmcnt(4)" ::: "memory");
    } else {
      asm volatile("s_waitcnt vmcnt(0)" ::: "memory");
    }
    __builtin_amdgcn_sched_barrier(0);
    __builtin_amdgcn_s_barrier();            // tiles kt, kt+1 visible to all waves
    __builtin_amdgcn_sched_barrier(0);

    const unsigned short* As0 = &LDS[(kt % 3) * 8192];
    const unsigned short* Bs0 = As0 + 4096;
    const unsigned short* As1 = &LDS[((kt + 1) % 3) * 8192];
    const unsigned short* Bs1 = As1 + 4096;

    // 2. frag reads for BOTH tiles; compiler interleaves reads(kt+1) with MFMA(kt)
    bf16x8 a0[4], b0[4], a1[4], b1[4];
#pragma unroll
    for (int i = 0; i < 4; ++i) {
      const int r = wm + i * 16 + lrow;
      const int cb = (klane >> 3) ^ ((r >> 1) & 3);
      a0[i] = *reinterpret_cast<const bf16x8*>(&As0[r * 32 + cb * 8]);
      a1[i] = *reinterpret_cast<const bf16x8*>(&As1[r * 32 + cb * 8]);
    }
#pragma unroll
    for (int j = 0; j < 4; ++j) {
      const int r = wn + j * 16 + lrow;
      const int cb = (klane >> 3) ^ ((r >> 1) & 3);
      b0[j] = *reinterpret_cast<const bf16x8*>(&Bs0[r * 32 + cb * 8]);
      b1[j] = *reinterpret_cast<const bf16x8*>(&Bs1[r * 32 + cb * 8]);
    }

    __builtin_amdgcn_s_setprio(1);
#pragma unroll
    for (int i = 0; i < 4; ++i)
#pragma unroll
      for (int j = 0; j < 4; ++j)
        acc[i][j] = __builtin_amdgcn_mfma_f32_16x16x32_bf16(a0[i], b0[j], acc[i][j], 0, 0, 0);
    __builtin_amdgcn_s_setprio(0);

    // 3. mid barrier: all waves' reads of set kt%3 are done (consumed by MFMA(kt));
    //    safe for STAGE(kt+3) to rewrite set (kt+3)%3 == kt%3.
    __builtin_amdgcn_sched_barrier(0);
    __builtin_amdgcn_s_barrier();
    __builtin_amdgcn_sched_barrier(0);

    // 4. stage kt+3; its loads fly under MFMA(kt+1)
    if (kt + 3 < ktiles) STAGE(kt + 3);

    __builtin_amdgcn_s_setprio(1);
#pragma unroll
    for (int i = 0; i < 4; ++i)
#pragma unroll
      for (int j = 0; j < 4; ++j)
        acc[i][j] = __builtin_amdgcn_mfma_f32_16x16x32_bf16(a1[i], b1[j], acc[i][j], 0, 0, 0);
    __builtin_amdgcn_s_setprio(0);

    // 5. end barrier: reads of set (kt+1)%3 consumed; next iter's STAGE(kt+4)
    //    (set (kt+1)%3) is safe.
    __builtin_amdgcn_sched_barrier(0);
    __builtin_amdgcn_s_barrier();
    __builtin_amdgcn_sched_barrier(0);
  }
#undef STAGE

  // ---- Epilogue (C/D map m89/m91): col=lane&15, row=(lane>>4)*4+r
  const int colbase = n0 + wn + (lane & 15);
  const int rowbase = m0 + wm + ((lane >> 4) << 2);
#pragma unroll
  for (int j = 0; j < 4; ++j) {
    const int col = colbase + j * 16;
    const float bv = Bias[col];
#pragma unroll
    for (int i = 0; i < 4; ++i) {
      const int row = rowbase + i * 16;
#pragma unroll
      for (int r = 0; r < 4; ++r)
        Out[(size_t)(row + r) * N + col] = acc[i][j][r] + bv;
    }
  }
}

extern "C" void kernel_launch(void* const* d_in, const int* in_sizes, int n_in,
                              void* d_out, int out_size, void* d_ws, size_t ws_size,
                              hipStream_t stream) {
  const float* x    = (const float*)d_in[0];
  const int*   q    = (const int*)d_in[1];
  const float* s    = (const float*)d_in[2];
  const float* z    = (const float*)d_in[3];
  const float* bias = (const float*)d_in[4];
  float*       out  = (float*)d_out;

  const int N  = in_sizes[4];              // 11008
  const int K  = in_sizes[1] / N;          // 4096
  const int M  = in_sizes[0] / K;          // 2048
  const int G  = in_sizes[2] / N;          // 32
  const int GS = K / G;                    // 128

  unsigned short* Wb = (unsigned short*)d_ws;            // N*K bf16 = 90MB
  unsigned short* Xb = Wb + (size_t)N * K;               // M*K bf16 = 17MB

  const int wblocks = (int)(((size_t)N * K / 8 + 255) / 256);
  wdequant_kernel<<<wblocks, 256, 0, stream>>>(q, s, z, Wb, N, K, GS);
  const int xblocks = (M * K / 8 + 255) / 256;
  xconv_kernel<<<xblocks, 256, 0, stream>>>(x, Xb, M, K);

  const int grid = (M / BM) * (N / BN);                  // 16*86 = 1376
  gemm_kernel<<<grid, NTHREADS, 0, stream>>>(Xb, Wb, bias, out, M, N, K);
}